// Round 7
// baseline (1766.111 us; speedup 1.0000x reference)
//
#include <hip/hip_runtime.h>
#include <math.h>

typedef __bf16 bf16;
typedef __bf16 bf16x8 __attribute__((ext_vector_type(8)));
typedef float f32x4 __attribute__((ext_vector_type(4)));

struct GemmP {
  const bf16* A;
  const bf16* B;
  long sA, sB, sO;   // batch strides in elements
  int K, ldo;
  void* out;
  const float* bias;
  const float* aux;  // dsum for EPI 2
};

__device__ __forceinline__ float gelu_f(float x) {
  return 0.5f * x * (1.f + tanhf(0.7978845608028654f * (x + 0.044715f * x * x * x)));
}

// async global->LDS, 16B per lane; LDS dest = wave-uniform base + lane*16
__device__ __forceinline__ void gload16(const bf16* g, bf16* l) {
  __builtin_amdgcn_global_load_lds(
      (const __attribute__((address_space(1))) void*)g,
      (__attribute__((address_space(3))) void*)l, 16, 0, 0);
}

// C = A @ B^T, A:[M,K] bf16 (lda=K), B:[N,K] bf16 (ldb=K), f32 accum.
// 128x128 tile, BK=64, 4 waves, 16x16x32 bf16 MFMA, global_load_lds staging (m97 structure).
// EPI: 0 = store bf16 (z*sO + row*ldo + col)
//      1 = +bias, scatter [b,n,h*128+d] -> [b,h,n,d] bf16   (M=8192 rows = b*2048+n)
//      2 = *1/aux[z*2048+row], scatter -> o[b,n, h*128+col]  (batch z = b*8+h, M=2048)
//      3 = y[row*ldo+col] += acc + bias[col]  (f32 out)
//      4 = store bf16 gelu(acc + bias[col])
template<int EPI>
__global__ __launch_bounds__(256) void gemm_bt(GemmP p) {
  __shared__ bf16 As[128][64];   // linear: global_load_lds dest must be unpadded
  __shared__ bf16 Bs[128][64];
  const int nt = blockIdx.x, mt = blockIdx.y, z = blockIdx.z;
  const bf16* A = p.A + (long)z * p.sA + (long)mt * 128 * p.K;
  const bf16* B = p.B + (long)z * p.sB + (long)nt * 128 * p.K;
  const int t = threadIdx.x;
  const int w = t >> 6, lane = t & 63;
  const int lr = lane & 15, lg = lane >> 4;
  const int wm = (w >> 1) * 64, wn = (w & 1) * 64;
  const int srow = lane >> 3, scol = (lane & 7) * 8;   // staging: 8 rows/wave-issue

  f32x4 acc[4][4] = {};

  for (int k0 = 0; k0 < p.K; k0 += 64) {
#pragma unroll
    for (int i = 0; i < 4; ++i) {
      int r0 = i * 32 + w * 8;
      gload16(A + (long)(r0 + srow) * p.K + k0 + scol, &As[r0][0]);
      gload16(B + (long)(r0 + srow) * p.K + k0 + scol, &Bs[r0][0]);
    }
    __syncthreads();
#pragma unroll
    for (int ks = 0; ks < 64; ks += 32) {
      bf16x8 af[4], bfr[4];
#pragma unroll
      for (int i = 0; i < 4; ++i) af[i] = *(const bf16x8*)(&As[wm + i * 16 + lr][ks + lg * 8]);
#pragma unroll
      for (int i = 0; i < 4; ++i) bfr[i] = *(const bf16x8*)(&Bs[wn + i * 16 + lr][ks + lg * 8]);
#pragma unroll
      for (int i = 0; i < 4; ++i)
#pragma unroll
        for (int j = 0; j < 4; ++j)
          acc[i][j] = __builtin_amdgcn_mfma_f32_16x16x32_bf16(af[i], bfr[j], acc[i][j], 0, 0, 0);
    }
    __syncthreads();
  }

#pragma unroll
  for (int i = 0; i < 4; ++i) {
#pragma unroll
    for (int j = 0; j < 4; ++j) {
#pragma unroll
      for (int e = 0; e < 4; ++e) {
        int grow = mt * 128 + wm + i * 16 + lg * 4 + e;
        int gcol = nt * 128 + wn + j * 16 + lr;
        float v = acc[i][j][e];
        if constexpr (EPI == 0) {
          ((bf16*)p.out)[(long)z * p.sO + (long)grow * p.ldo + gcol] = (bf16)v;
        } else if constexpr (EPI == 1) {
          v += p.bias[gcol];
          int b = grow >> 11, n = grow & 2047, hh = gcol >> 7, d = gcol & 127;
          ((bf16*)p.out)[(((long)(b * 8 + hh) * 2048 + n) << 7) + d] = (bf16)v;
        } else if constexpr (EPI == 2) {
          float ds = p.aux[(long)z * 2048 + grow];
          int b = z >> 3, hh = z & 7;
          ((bf16*)p.out)[((long)(b * 2048 + grow)) * 1024 + hh * 128 + gcol] = (bf16)(v / ds);
        } else if constexpr (EPI == 3) {
          float* Y = (float*)p.out;
          Y[(long)grow * p.ldo + gcol] += v + p.bias[gcol];
        } else {
          float vv = v + p.bias[gcol];
          ((bf16*)p.out)[(long)grow * p.ldo + gcol] = (bf16)gelu_f(vv);
        }
      }
    }
  }
}

// out[z][c][r] = (bf16) in[z][r][c] ; R,C multiples of 32
template<typename TIN>
__global__ void transpose_cast(const TIN* __restrict__ in, bf16* __restrict__ out,
                               int R, int C, long sIn, long sOut) {
  __shared__ float tile[32][33];
  in += (long)blockIdx.z * sIn;
  out += (long)blockIdx.z * sOut;
  int r0 = blockIdx.y * 32, c0 = blockIdx.x * 32;
  int tx = threadIdx.x, ty = threadIdx.y;  // (32,8)
#pragma unroll
  for (int i = 0; i < 4; ++i)
    tile[ty + i * 8][tx] = (float)in[(long)(r0 + ty + i * 8) * C + c0 + tx];
  __syncthreads();
#pragma unroll
  for (int i = 0; i < 4; ++i)
    out[(long)(c0 + ty + i * 8) * R + r0 + tx] = (bf16)tile[tx][ty + i * 8];
}

// pm_n[l][f][d] = f<621 ? proj[l][f][d]*norm : 0   (norm = 128^-0.25)
__global__ void pm_prep(const float* __restrict__ proj, bf16* __restrict__ out) {
  int f = blockIdx.x, z = blockIdx.y, d = threadIdx.x;  // block 128
  float v = (f < 621) ? proj[((long)z * 621 + f) * 128 + d] * 0.29730177875068026f : 0.f;
  out[((long)z * 640 + f) * 128 + d] = (bf16)v;
}

__global__ __launch_bounds__(128) void enc_k(const float* __restrict__ x, const float* __restrict__ w,
                                             const float* __restrict__ b, float* __restrict__ y) {
  __shared__ float xs[40];
  int r = blockIdx.x, t = threadIdx.x;
  if (t < 35) xs[t] = x[(long)r * 35 + t];
  __syncthreads();
  float acc = b[t];
#pragma unroll
  for (int m = 0; m < 35; ++m) acc += xs[m] * w[m * 128 + t];
  y[(long)r * 128 + t] = acc;
}

__global__ __launch_bounds__(256) void ln_k(const float* __restrict__ y, const float* __restrict__ g,
                                            const float* __restrict__ b, bf16* __restrict__ out) {
  int w = threadIdx.x >> 6, lane = threadIdx.x & 63;
  long r = (long)blockIdx.x * 4 + w;
  const float* yr = y + r * 128;
  float e0 = yr[lane], e1 = yr[lane + 64];
  float s = e0 + e1, q = e0 * e0 + e1 * e1;
  for (int o = 32; o; o >>= 1) { s += __shfl_xor(s, o); q += __shfl_xor(q, o); }
  float mean = s * (1.f / 128.f);
  float var = q * (1.f / 128.f) - mean * mean;
  float rs = rsqrtf(var + 1e-5f);
  out[r * 128 + lane] = (bf16)((e0 - mean) * rs * g[lane] + b[lane]);
  out[r * 128 + lane + 64] = (bf16)((e1 - mean) * rs * g[lane + 64] + b[lane + 64]);
}

// diag[r] = 0.5*norm^2 * sum_d q[r,d]^2   (0.5/sqrt(128))
__global__ __launch_bounds__(256) void diag_kernel(const bf16* __restrict__ q, float* __restrict__ dg) {
  int w = threadIdx.x >> 6, lane = threadIdx.x & 63;
  long r = (long)blockIdx.x * 4 + w;
  const bf16* p = q + r * 128;
  float e0 = (float)p[lane], e1 = (float)p[lane + 64];
  float s = e0 * e0 + e1 * e1;
  for (int o = 32; o; o >>= 1) s += __shfl_xor(s, o);
  if (!lane) dg[r] = s * 0.04419417382415922f;
}

__global__ __launch_bounds__(256) void rowmax_k(const bf16* __restrict__ x, float* __restrict__ mx,
                                                int C, int LIM) {
  int w = threadIdx.x >> 6, lane = threadIdx.x & 63;
  long r = (long)blockIdx.x * 4 + w;
  const bf16* p = x + r * C;
  float m = -3.0e38f;
  for (int c = lane; c < LIM; c += 64) m = fmaxf(m, (float)p[c]);
  for (int o = 32; o; o >>= 1) m = fmaxf(m, __shfl_xor(m, o));
  if (!lane) mx[r] = m;
}

__global__ __launch_bounds__(256) void kmax2_k(const float* __restrict__ km1, float* __restrict__ mxk) {
  __shared__ float red[256];
  int bh = blockIdx.x, t = threadIdx.x;
  float m = -3.0e38f;
  for (int f = t; f < 621; f += 256) m = fmaxf(m, km1[bh * 640 + f]);
  red[t] = m;
  __syncthreads();
  for (int s = 128; s; s >>= 1) { if (t < s) red[t] = fmaxf(red[t], red[t + s]); __syncthreads(); }
  if (!t) mxk[bh] = red[0];
}

// in-place: xkt[bh][f][n] -> kf = ratio*(exp(xp - diag_k[bh,n] - mxk[bh]) + 1e-4); pad rows -> 0
// also ksum[bh][f] = sum_n kf (from rounded bf16)
__global__ __launch_bounds__(256) void ktrans_k(bf16* __restrict__ xkt, const float* __restrict__ diagk,
                                                const float* __restrict__ mxk, float* __restrict__ ksum) {
  int f = blockIdx.x, bh = blockIdx.y, t = threadIdx.x;
  bf16* row = xkt + ((long)bh * 640 + f) * 2048;
  float acc = 0.f;
  if (f < 621) {
    float mx = mxk[bh];
    const float* dgp = diagk + (long)bh * 2048;
#pragma unroll
    for (int i = 0; i < 8; ++i) {
      int n = t + i * 256;
      float xv = (float)row[n];
      float kf = 0.040128573f * (expf(xv - dgp[n] - mx) + 1e-4f);
      bf16 kb = (bf16)kf;
      row[n] = kb;
      acc += (float)kb;
    }
  } else {
#pragma unroll
    for (int i = 0; i < 8; ++i) row[t + i * 256] = (bf16)0.f;
  }
  __shared__ float red[256];
  red[t] = acc;
  __syncthreads();
  for (int s = 128; s; s >>= 1) { if (t < s) red[t] += red[t + s]; __syncthreads(); }
  if (!t) ksum[(long)bh * 640 + f] = red[0];
}

// in-place: xq[r][f] -> qf; pad cols -> 0; dsum[r] = sum_f qf*ksum[bh][f]
__global__ __launch_bounds__(256) void qtrans_k(bf16* __restrict__ xq, const float* __restrict__ diagq,
                                                const float* __restrict__ mxq, const float* __restrict__ ksum,
                                                float* __restrict__ dsum) {
  long r = blockIdx.x;
  int t = threadIdx.x;
  int bh = (int)(r >> 11);
  bf16* row = xq + r * 640;
  const float* ks = ksum + (long)bh * 640;
  float dg = diagq[r], mx = mxq[r];
  float acc = 0.f;
#pragma unroll
  for (int i = 0; i < 3; ++i) {
    int f = t + i * 256;
    if (f >= 640) break;
    if (f < 621) {
      float xv = (float)row[f];
      float qf = 0.040128573f * (expf(xv - dg - mx) + 1e-4f);
      bf16 qb = (bf16)qf;
      row[f] = qb;
      acc += (float)qb * ks[f];
    } else {
      row[f] = (bf16)0.f;
    }
  }
  __shared__ float red[256];
  red[t] = acc;
  __syncthreads();
  for (int s = 128; s; s >>= 1) { if (t < s) red[t] += red[t + s]; __syncthreads(); }
  if (!t) dsum[r] = red[0];
}

__global__ __launch_bounds__(256) void dec_kernel(const float* __restrict__ y, const float* __restrict__ w,
                                                  const float* __restrict__ b, float* __restrict__ out) {
  int wv = threadIdx.x >> 6, lane = threadIdx.x & 63;
  long r = (long)blockIdx.x * 4 + wv;
  const float* yr = y + r * 128;
  float s = yr[lane] * w[lane] + yr[lane + 64] * w[lane + 64];
  for (int o = 32; o; o >>= 1) s += __shfl_xor(s, o);
  if (!lane) out[r] = s + b[0];
}

extern "C" void kernel_launch(void* const* d_in, const int* in_sizes, int n_in,
                              void* d_out, int out_size, void* d_ws, size_t ws_size,
                              hipStream_t stream) {
  (void)in_sizes; (void)n_in; (void)out_size; (void)ws_size;
  const float* x     = (const float*)d_in[0];
  const float* enc_w = (const float*)d_in[1];
  const float* enc_b = (const float*)d_in[2];
  const float* ln1_g = (const float*)d_in[3];
  const float* ln1_b = (const float*)d_in[4];
  const float* wq    = (const float*)d_in[5];
  const float* bq    = (const float*)d_in[6];
  const float* wk    = (const float*)d_in[7];
  const float* bk    = (const float*)d_in[8];
  const float* wv    = (const float*)d_in[9];
  const float* bv    = (const float*)d_in[10];
  const float* wo    = (const float*)d_in[11];
  const float* bo    = (const float*)d_in[12];
  const float* ln2_g = (const float*)d_in[13];
  const float* ln2_b = (const float*)d_in[14];
  const float* w1    = (const float*)d_in[15];
  const float* b1    = (const float*)d_in[16];
  const float* w2    = (const float*)d_in[17];
  const float* b2    = (const float*)d_in[18];
  const float* proj  = (const float*)d_in[19];
  const float* dec_w = (const float*)d_in[20];
  const float* dec_b = (const float*)d_in[21];
  float* out = (float*)d_out;

  char* ws = (char*)d_ws;
  size_t off = 0;
  auto alloc = [&](size_t bytes) -> void* {
    void* p = ws + off;
    off = (off + bytes + 255) & ~(size_t)255;
    return p;
  };

  float* y    = (float*)alloc(4ul * 8192 * 128);
  bf16* hbf   = (bf16*)alloc(2ul * 8192 * 128);
  bf16* qb    = (bf16*)alloc(2ul * 65536 * 128);
  bf16* kb    = (bf16*)alloc(2ul * 65536 * 128);   // reused as o_buf
  bf16* vb    = (bf16*)alloc(2ul * 65536 * 128);
  bf16* vt    = (bf16*)alloc(2ul * 65536 * 128);   // reused as g_buf
  bf16* xqk   = (bf16*)alloc(2ul * 65536 * 640);   // xp_k^T then xp_q/qf
  bf16* ctxt  = (bf16*)alloc(2ul * 32 * 128 * 640);
  float* diagq = (float*)alloc(4ul * 65536);
  float* diagk = (float*)alloc(4ul * 65536);
  float* mxq   = (float*)alloc(4ul * 65536);
  float* kmax1 = (float*)alloc(4ul * 20480);
  float* mxk   = (float*)alloc(4ul * 32);
  float* ksum  = (float*)alloc(4ul * 32 * 640);
  float* dsum  = (float*)alloc(4ul * 65536);
  bf16* wqT = (bf16*)alloc(2ul * 4 * 1024 * 128);
  bf16* wkT = (bf16*)alloc(2ul * 4 * 1024 * 128);
  bf16* wvT = (bf16*)alloc(2ul * 4 * 1024 * 128);
  bf16* woT = (bf16*)alloc(2ul * 4 * 128 * 1024);
  bf16* w1T = (bf16*)alloc(2ul * 4 * 512 * 128);
  bf16* w2T = (bf16*)alloc(2ul * 4 * 128 * 512);
  bf16* pmn = (bf16*)alloc(2ul * 4 * 640 * 128);
  bf16* ob = kb;
  bf16* gb = vt;

  auto launch_gemm = [&](int epi, const bf16* A, const bf16* B, long sA, long sB, long sO,
                         int K, int ldo, void* o, const float* bias, const float* aux, dim3 grid) {
    GemmP gp;
    gp.A = A; gp.B = B; gp.sA = sA; gp.sB = sB; gp.sO = sO;
    gp.K = K; gp.ldo = ldo; gp.out = o; gp.bias = bias; gp.aux = aux;
    switch (epi) {
      case 0: gemm_bt<0><<<grid, 256, 0, stream>>>(gp); break;
      case 1: gemm_bt<1><<<grid, 256, 0, stream>>>(gp); break;
      case 2: gemm_bt<2><<<grid, 256, 0, stream>>>(gp); break;
      case 3: gemm_bt<3><<<grid, 256, 0, stream>>>(gp); break;
      case 4: gemm_bt<4><<<grid, 256, 0, stream>>>(gp); break;
    }
  };

  dim3 tb(32, 8);
  // weight prep (per call; weights are inputs)
  transpose_cast<float><<<dim3(32, 4, 4), tb, 0, stream>>>(wq, wqT, 128, 1024, 131072, 131072);
  transpose_cast<float><<<dim3(32, 4, 4), tb, 0, stream>>>(wk, wkT, 128, 1024, 131072, 131072);
  transpose_cast<float><<<dim3(32, 4, 4), tb, 0, stream>>>(wv, wvT, 128, 1024, 131072, 131072);
  transpose_cast<float><<<dim3(4, 32, 4), tb, 0, stream>>>(wo, woT, 1024, 128, 131072, 131072);
  transpose_cast<float><<<dim3(16, 4, 4), tb, 0, stream>>>(w1, w1T, 128, 512, 65536, 65536);
  transpose_cast<float><<<dim3(4, 16, 4), tb, 0, stream>>>(w2, w2T, 512, 128, 65536, 65536);
  pm_prep<<<dim3(640, 4), 128, 0, stream>>>(proj, pmn);

  enc_k<<<8192, 128, 0, stream>>>(x, enc_w, enc_b, y);

  for (int i = 0; i < 4; ++i) {
    const bf16* wqTl = wqT + (long)i * 131072;
    const bf16* wkTl = wkT + (long)i * 131072;
    const bf16* wvTl = wvT + (long)i * 131072;
    const bf16* woTl = woT + (long)i * 131072;
    const bf16* w1Tl = w1T + (long)i * 65536;
    const bf16* w2Tl = w2T + (long)i * 65536;
    const bf16* pml  = pmn + (long)i * 81920;

    ln_k<<<2048, 256, 0, stream>>>(y, ln1_g + i * 128, ln1_b + i * 128, hbf);
    // q,k,v : [8192,128]@[128,1024] -> scatter to [b,h,n,d]
    launch_gemm(1, hbf, wqTl, 0, 0, 0, 128, 0, qb, bq + i * 1024, nullptr, dim3(8, 64, 1));
    launch_gemm(1, hbf, wkTl, 0, 0, 0, 128, 0, kb, bk + i * 1024, nullptr, dim3(8, 64, 1));
    launch_gemm(1, hbf, wvTl, 0, 0, 0, 128, 0, vb, bv + i * 1024, nullptr, dim3(8, 64, 1));
    // v^T per (b,h): [2048,128] -> [128,2048]
    transpose_cast<bf16><<<dim3(4, 64, 32), tb, 0, stream>>>(vb, vt, 2048, 128, 262144, 262144);
    diag_kernel<<<16384, 256, 0, stream>>>(qb, diagq);
    diag_kernel<<<16384, 256, 0, stream>>>(kb, diagk);
    // xp_k^T[bh] = pm_n @ k^T : [640,128]@[2048,128]^T -> [640,2048]
    launch_gemm(0, pml, kb, 0, 262144, 1310720, 128, 2048, xqk, nullptr, nullptr, dim3(16, 5, 32));
    rowmax_k<<<5120, 256, 0, stream>>>(xqk, kmax1, 2048, 2048);
    kmax2_k<<<32, 256, 0, stream>>>(kmax1, mxk);
    ktrans_k<<<dim3(640, 32), 256, 0, stream>>>(xqk, diagk, mxk, ksum);
    // ctx^T[bh] = v^T @ kf^T^T : A=vt[128,2048], B=kf[640,2048] -> [128,640]
    launch_gemm(0, vt, xqk, 262144, 1310720, 81920, 2048, 640, ctxt, nullptr, nullptr, dim3(5, 1, 32));
    // xp_q = q @ pm_n^T : [65536,128]@[640,128]^T -> [65536,640]
    launch_gemm(0, qb, pml, 0, 0, 0, 128, 640, xqk, nullptr, nullptr, dim3(5, 512, 1));
    rowmax_k<<<16384, 256, 0, stream>>>(xqk, mxq, 640, 621);
    qtrans_k<<<65536, 256, 0, stream>>>(xqk, diagq, mxq, ksum, dsum);
    // o[bh] = qf @ ctx^T^T : A=qf[2048,640], B=ctxt[128,640] -> scatter [b,n,h*128+d], *dinv
    launch_gemm(2, xqk, ctxt, 1310720, 81920, 0, 640, 0, ob, nullptr, dsum, dim3(1, 16, 32));
    // y += o @ wo + bo
    launch_gemm(3, ob, woTl, 0, 0, 0, 1024, 128, y, bo + i * 128, nullptr, dim3(1, 64, 1));
    ln_k<<<2048, 256, 0, stream>>>(y, ln2_g + i * 128, ln2_b + i * 128, hbf);
    // g = gelu(h@w1+b1)
    launch_gemm(4, hbf, w1Tl, 0, 0, 0, 128, 512, gb, b1 + i * 512, nullptr, dim3(4, 64, 1));
    // y += g@w2 + b2
    launch_gemm(3, gb, w2Tl, 0, 0, 0, 512, 128, y, b2 + i * 128, nullptr, dim3(1, 64, 1));
  }

  dec_kernel<<<2048, 256, 0, stream>>>(y, dec_w, dec_b, out);
}

// Round 10
// 1440.158 us; speedup vs baseline: 1.2263x; 1.2263x over previous
//
#include <hip/hip_runtime.h>
#include <math.h>

typedef __bf16 bf16;
typedef __bf16 bf16x8 __attribute__((ext_vector_type(8)));
typedef float f32x4 __attribute__((ext_vector_type(4)));

struct GemmP {
  const bf16* A;
  const bf16* B;
  long sA, sB, sO;   // batch strides in elements
  int K, ldo;
  void* out;
  const float* bias;
  const float* aux;  // dsum for EPI 2
  float* aux2;       // tilemax out for EPI 5
};

__device__ __forceinline__ float gelu_f(float x) {
  return 0.5f * x * (1.f + tanhf(0.7978845608028654f * (x + 0.044715f * x * x * x)));
}

// async global->LDS, 16B per lane; LDS dest = wave-uniform base + lane*16
__device__ __forceinline__ void gload16(const bf16* g, bf16* l) {
  __builtin_amdgcn_global_load_lds(
      (const __attribute__((address_space(1))) void*)g,
      (__attribute__((address_space(3))) void*)l, 16, 0, 0);
}

// C = A @ B^T, A:[M,K] bf16 (lda=K), B:[N,K] bf16 (ldb=K), f32 accum.
// 128x128 tile, BK=64, 4 waves, 16x16x32 bf16 MFMA, global_load_lds staging (m97 structure).
// EPI: 0 = store bf16 (z*sO + row*ldo + col)
//      1 = +bias, scatter [b,n,h*128+d] -> [b,h,n,d] bf16   (M=8192 rows = b*2048+n)
//      2 = *1/aux[z*2048+row], scatter -> o[b,n, h*128+col]  (batch z = b*8+h, M=2048)
//      3 = y[row*ldo+col] += acc + bias[col]  (f32 out)
//      4 = store bf16 gelu(acc + bias[col])
//      5 = EPI0 store + masked (row<621) block max -> aux2[z*80 + mt*16 + nt]
template<int EPI>
__global__ __launch_bounds__(256) void gemm_bt(GemmP p) {
  __shared__ bf16 As[128][64];   // linear: global_load_lds dest must be unpadded
  __shared__ bf16 Bs[128][64];
  const int nt = blockIdx.x, mt = blockIdx.y, z = blockIdx.z;
  const bf16* A = p.A + (long)z * p.sA + (long)mt * 128 * p.K;
  const bf16* B = p.B + (long)z * p.sB + (long)nt * 128 * p.K;
  const int t = threadIdx.x;
  const int w = t >> 6, lane = t & 63;
  const int lr = lane & 15, lg = lane >> 4;
  const int wm = (w >> 1) * 64, wn = (w & 1) * 64;
  const int srow = lane >> 3, scol = (lane & 7) * 8;   // staging: 8 rows/wave-issue

  f32x4 acc[4][4] = {};

  for (int k0 = 0; k0 < p.K; k0 += 64) {
#pragma unroll
    for (int i = 0; i < 4; ++i) {
      int r0 = i * 32 + w * 8;
      gload16(A + (long)(r0 + srow) * p.K + k0 + scol, &As[r0][0]);
      gload16(B + (long)(r0 + srow) * p.K + k0 + scol, &Bs[r0][0]);
    }
    __syncthreads();
#pragma unroll
    for (int ks = 0; ks < 64; ks += 32) {
      bf16x8 af[4], bfr[4];
#pragma unroll
      for (int i = 0; i < 4; ++i) af[i] = *(const bf16x8*)(&As[wm + i * 16 + lr][ks + lg * 8]);
#pragma unroll
      for (int i = 0; i < 4; ++i) bfr[i] = *(const bf16x8*)(&Bs[wn + i * 16 + lr][ks + lg * 8]);
#pragma unroll
      for (int i = 0; i < 4; ++i)
#pragma unroll
        for (int j = 0; j < 4; ++j)
          acc[i][j] = __builtin_amdgcn_mfma_f32_16x16x32_bf16(af[i], bfr[j], acc[i][j], 0, 0, 0);
    }
    __syncthreads();
  }

  float tmax = -3.0e38f;
#pragma unroll
  for (int i = 0; i < 4; ++i) {
#pragma unroll
    for (int j = 0; j < 4; ++j) {
#pragma unroll
      for (int e = 0; e < 4; ++e) {
        int grow = mt * 128 + wm + i * 16 + lg * 4 + e;
        int gcol = nt * 128 + wn + j * 16 + lr;
        float v = acc[i][j][e];
        if constexpr (EPI == 0) {
          ((bf16*)p.out)[(long)z * p.sO + (long)grow * p.ldo + gcol] = (bf16)v;
        } else if constexpr (EPI == 1) {
          v += p.bias[gcol];
          int b = grow >> 11, n = grow & 2047, hh = gcol >> 7, d = gcol & 127;
          ((bf16*)p.out)[(((long)(b * 8 + hh) * 2048 + n) << 7) + d] = (bf16)v;
        } else if constexpr (EPI == 2) {
          float ds = p.aux[(long)z * 2048 + grow];
          int b = z >> 3, hh = z & 7;
          ((bf16*)p.out)[((long)(b * 2048 + grow)) * 1024 + hh * 128 + gcol] = (bf16)(v / ds);
        } else if constexpr (EPI == 3) {
          float* Y = (float*)p.out;
          Y[(long)grow * p.ldo + gcol] += v + p.bias[gcol];
        } else if constexpr (EPI == 4) {
          float vv = v + p.bias[gcol];
          ((bf16*)p.out)[(long)grow * p.ldo + gcol] = (bf16)gelu_f(vv);
        } else {  // EPI 5
          ((bf16*)p.out)[(long)z * p.sO + (long)grow * p.ldo + gcol] = (bf16)v;
          if (grow < 621) tmax = fmaxf(tmax, v);
        }
      }
    }
  }
  if constexpr (EPI == 5) {
    for (int o = 32; o; o >>= 1) tmax = fmaxf(tmax, __shfl_xor(tmax, o));
    __shared__ float red4[4];
    if (!lane) red4[w] = tmax;
    __syncthreads();
    if (!t) p.aux2[(long)z * 80 + mt * 16 + nt] =
        fmaxf(fmaxf(red4[0], red4[1]), fmaxf(red4[2], red4[3]));
  }
}

// out[z][c][r] = (bf16) in[z][r][c] ; R,C multiples of 32
template<typename TIN>
__global__ void transpose_cast(const TIN* __restrict__ in, bf16* __restrict__ out,
                               int R, int C, long sIn, long sOut) {
  __shared__ float tile[32][33];
  in += (long)blockIdx.z * sIn;
  out += (long)blockIdx.z * sOut;
  int r0 = blockIdx.y * 32, c0 = blockIdx.x * 32;
  int tx = threadIdx.x, ty = threadIdx.y;  // (32,8)
#pragma unroll
  for (int i = 0; i < 4; ++i)
    tile[ty + i * 8][tx] = (float)in[(long)(r0 + ty + i * 8) * C + c0 + tx];
  __syncthreads();
#pragma unroll
  for (int i = 0; i < 4; ++i)
    out[(long)(c0 + ty + i * 8) * R + r0 + tx] = (bf16)tile[tx][ty + i * 8];
}

// pm_n[l][f][d] = f<621 ? proj[l][f][d]*norm : 0   (norm = 128^-0.25)
__global__ void pm_prep(const float* __restrict__ proj, bf16* __restrict__ out) {
  int f = blockIdx.x, z = blockIdx.y, d = threadIdx.x;  // block 128
  float v = (f < 621) ? proj[((long)z * 621 + f) * 128 + d] * 0.29730177875068026f : 0.f;
  out[((long)z * 640 + f) * 128 + d] = (bf16)v;
}

__global__ __launch_bounds__(128) void enc_k(const float* __restrict__ x, const float* __restrict__ w,
                                             const float* __restrict__ b, float* __restrict__ y) {
  __shared__ float xs[40];
  int r = blockIdx.x, t = threadIdx.x;
  if (t < 35) xs[t] = x[(long)r * 35 + t];
  __syncthreads();
  float acc = b[t];
#pragma unroll
  for (int m = 0; m < 35; ++m) acc += xs[m] * w[m * 128 + t];
  y[(long)r * 128 + t] = acc;
}

__global__ __launch_bounds__(256) void ln_k(const float* __restrict__ y, const float* __restrict__ g,
                                            const float* __restrict__ b, bf16* __restrict__ out) {
  int w = threadIdx.x >> 6, lane = threadIdx.x & 63;
  long r = (long)blockIdx.x * 4 + w;
  const float* yr = y + r * 128;
  float e0 = yr[lane], e1 = yr[lane + 64];
  float s = e0 + e1, q = e0 * e0 + e1 * e1;
  for (int o = 32; o; o >>= 1) { s += __shfl_xor(s, o); q += __shfl_xor(q, o); }
  float mean = s * (1.f / 128.f);
  float var = q * (1.f / 128.f) - mean * mean;
  float rs = rsqrtf(var + 1e-5f);
  out[r * 128 + lane] = (bf16)((e0 - mean) * rs * g[lane] + b[lane]);
  out[r * 128 + lane + 64] = (bf16)((e1 - mean) * rs * g[lane + 64] + b[lane + 64]);
}

// diag[r] = 0.5*norm^2 * sum_d q[r,d]^2 ; 16 lanes x bf16x8 per row, 16 rows/block
__global__ __launch_bounds__(256) void diag_kernel(const bf16* __restrict__ q, float* __restrict__ dg) {
  int wv = threadIdx.x >> 6, lane = threadIdx.x & 63;
  int sub = lane >> 4, sl = lane & 15;
  long r = (long)blockIdx.x * 16 + wv * 4 + sub;
  bf16x8 v = *(const bf16x8*)(q + r * 128 + sl * 8);
  float s = 0.f;
#pragma unroll
  for (int j = 0; j < 8; ++j) { float e = (float)v[j]; s += e * e; }
  for (int o = 8; o; o >>= 1) s += __shfl_xor(s, o);
  if (!sl) dg[r] = s * 0.04419417382415922f;
}

// reduce 80 tile-maxes per bh
__global__ __launch_bounds__(64) void kmax2_k(const float* __restrict__ tm, float* __restrict__ mxk) {
  int bh = blockIdx.x, lane = threadIdx.x;
  const float* p = tm + bh * 80;
  float m = p[lane];
  if (lane < 16) m = fmaxf(m, p[64 + lane]);
  for (int o = 32; o; o >>= 1) m = fmaxf(m, __shfl_xor(m, o));
  if (!lane) mxk[bh] = m;
}

// in-place vectorized: xkt[bh][f][n] -> kf; pad rows -> 0; ksum[bh][f] = sum_n kf
__global__ __launch_bounds__(256) void ktrans_k(bf16* __restrict__ xkt, const float* __restrict__ diagk,
                                                const float* __restrict__ mxk, float* __restrict__ ksum) {
  int f = blockIdx.x, bh = blockIdx.y, t = threadIdx.x;
  bf16* row = xkt + ((long)bh * 640 + f) * 2048;
  float acc = 0.f;
  if (f < 621) {
    float mx = mxk[bh];
    const float* dgp = diagk + (long)bh * 2048 + t * 8;
    float4 d0 = *(const float4*)(dgp);
    float4 d1 = *(const float4*)(dgp + 4);
    float dd[8] = {d0.x, d0.y, d0.z, d0.w, d1.x, d1.y, d1.z, d1.w};
    bf16x8 v = *(const bf16x8*)(row + t * 8);
    bf16x8 o;
#pragma unroll
    for (int j = 0; j < 8; ++j) {
      float kf = 0.040128573f * (expf((float)v[j] - dd[j] - mx) + 1e-4f);
      bf16 kb = (bf16)kf;
      o[j] = kb;
      acc += (float)kb;
    }
    *(bf16x8*)(row + t * 8) = o;
  } else {
    bf16x8 zz = {};
    *(bf16x8*)(row + t * 8) = zz;
  }
  for (int o = 32; o; o >>= 1) acc += __shfl_xor(acc, o);
  __shared__ float red[4];
  if (!(t & 63)) red[t >> 6] = acc;
  __syncthreads();
  if (!t) ksum[(long)bh * 640 + f] = red[0] + red[1] + red[2] + red[3];
}

// fused in-place: rowmax + transform + dsum. One wave per row (4 rows/block).
__global__ __launch_bounds__(256) void qtrans_k(bf16* __restrict__ xq, const float* __restrict__ diagq,
                                                const float* __restrict__ ksum, float* __restrict__ dsum) {
  int wv = threadIdx.x >> 6, lane = threadIdx.x & 63;
  long r = (long)blockIdx.x * 4 + wv;
  int bh = (int)(r >> 11);
  bf16* row = xq + r * 640;
  const float* ks = ksum + (long)bh * 640;
  bool has2 = lane < 16;
  bf16x8 v0 = *(const bf16x8*)(row + lane * 8);
  bf16x8 v1 = {};
  if (has2) v1 = *(const bf16x8*)(row + 512 + lane * 8);
  float m = -3.0e38f;
#pragma unroll
  for (int j = 0; j < 8; ++j) m = fmaxf(m, (float)v0[j]);  // f<512 always valid
  if (has2) {
#pragma unroll
    for (int j = 0; j < 8; ++j) {
      int f = 512 + lane * 8 + j;
      if (f < 621) m = fmaxf(m, (float)v1[j]);
    }
  }
  for (int o = 32; o; o >>= 1) m = fmaxf(m, __shfl_xor(m, o));
  float base = -diagq[r] - m;
  float4 ka = *(const float4*)(ks + lane * 8);
  float4 kb2 = *(const float4*)(ks + lane * 8 + 4);
  float kk[8] = {ka.x, ka.y, ka.z, ka.w, kb2.x, kb2.y, kb2.z, kb2.w};
  float acc = 0.f;
  bf16x8 o0, o1;
#pragma unroll
  for (int j = 0; j < 8; ++j) {
    float qf = 0.040128573f * (expf((float)v0[j] + base) + 1e-4f);
    bf16 qb = (bf16)qf;
    o0[j] = qb;
    acc += (float)qb * kk[j];
  }
  *(bf16x8*)(row + lane * 8) = o0;
  if (has2) {
    float4 kc = *(const float4*)(ks + 512 + lane * 8);
    float4 kd = *(const float4*)(ks + 512 + lane * 8 + 4);
    float k2[8] = {kc.x, kc.y, kc.z, kc.w, kd.x, kd.y, kd.z, kd.w};
#pragma unroll
    for (int j = 0; j < 8; ++j) {
      int f = 512 + lane * 8 + j;
      if (f < 621) {
        float qf = 0.040128573f * (expf((float)v1[j] + base) + 1e-4f);
        bf16 qb = (bf16)qf;
        o1[j] = qb;
        acc += (float)qb * k2[j];
      } else {
        o1[j] = (bf16)0.f;
      }
    }
    *(bf16x8*)(row + 512 + lane * 8) = o1;
  }
  for (int o = 32; o; o >>= 1) acc += __shfl_xor(acc, o);
  if (!lane) dsum[r] = acc;
}

__global__ __launch_bounds__(256) void dec_kernel(const float* __restrict__ y, const float* __restrict__ w,
                                                  const float* __restrict__ b, float* __restrict__ out) {
  int wv = threadIdx.x >> 6, lane = threadIdx.x & 63;
  long r = (long)blockIdx.x * 4 + wv;
  const float* yr = y + r * 128;
  float s = yr[lane] * w[lane] + yr[lane + 64] * w[lane + 64];
  for (int o = 32; o; o >>= 1) s += __shfl_xor(s, o);
  if (!lane) out[r] = s + b[0];
}

extern "C" void kernel_launch(void* const* d_in, const int* in_sizes, int n_in,
                              void* d_out, int out_size, void* d_ws, size_t ws_size,
                              hipStream_t stream) {
  (void)in_sizes; (void)n_in; (void)out_size; (void)ws_size;
  const float* x     = (const float*)d_in[0];
  const float* enc_w = (const float*)d_in[1];
  const float* enc_b = (const float*)d_in[2];
  const float* ln1_g = (const float*)d_in[3];
  const float* ln1_b = (const float*)d_in[4];
  const float* wq    = (const float*)d_in[5];
  const float* bq    = (const float*)d_in[6];
  const float* wk    = (const float*)d_in[7];
  const float* bk    = (const float*)d_in[8];
  const float* wv    = (const float*)d_in[9];
  const float* bv    = (const float*)d_in[10];
  const float* wo    = (const float*)d_in[11];
  const float* bo    = (const float*)d_in[12];
  const float* ln2_g = (const float*)d_in[13];
  const float* ln2_b = (const float*)d_in[14];
  const float* w1    = (const float*)d_in[15];
  const float* b1    = (const float*)d_in[16];
  const float* w2    = (const float*)d_in[17];
  const float* b2    = (const float*)d_in[18];
  const float* proj  = (const float*)d_in[19];
  const float* dec_w = (const float*)d_in[20];
  const float* dec_b = (const float*)d_in[21];
  float* out = (float*)d_out;

  char* ws = (char*)d_ws;
  size_t off = 0;
  auto alloc = [&](size_t bytes) -> void* {
    void* p = ws + off;
    off = (off + bytes + 255) & ~(size_t)255;
    return p;
  };

  float* y    = (float*)alloc(4ul * 8192 * 128);
  bf16* hbf   = (bf16*)alloc(2ul * 8192 * 128);
  bf16* qb    = (bf16*)alloc(2ul * 65536 * 128);
  bf16* kb    = (bf16*)alloc(2ul * 65536 * 128);   // reused as o_buf
  bf16* vb    = (bf16*)alloc(2ul * 65536 * 128);
  bf16* vt    = (bf16*)alloc(2ul * 65536 * 128);   // reused as g_buf
  bf16* xqk   = (bf16*)alloc(2ul * 65536 * 640);   // xp_k^T then xp_q/qf
  bf16* ctxt  = (bf16*)alloc(2ul * 32 * 128 * 640);
  float* diagq = (float*)alloc(4ul * 65536);
  float* diagk = (float*)alloc(4ul * 65536);
  float* tilemax = (float*)alloc(4ul * 32 * 80);
  float* mxk   = (float*)alloc(4ul * 32);
  float* ksum  = (float*)alloc(4ul * 32 * 640);
  float* dsum  = (float*)alloc(4ul * 65536);
  bf16* wqT = (bf16*)alloc(2ul * 4 * 1024 * 128);
  bf16* wkT = (bf16*)alloc(2ul * 4 * 1024 * 128);
  bf16* wvT = (bf16*)alloc(2ul * 4 * 1024 * 128);
  bf16* woT = (bf16*)alloc(2ul * 4 * 128 * 1024);
  bf16* w1T = (bf16*)alloc(2ul * 4 * 512 * 128);
  bf16* w2T = (bf16*)alloc(2ul * 4 * 128 * 512);
  bf16* pmn = (bf16*)alloc(2ul * 4 * 640 * 128);
  bf16* ob = kb;
  bf16* gb = vt;

  auto launch_gemm = [&](int epi, const bf16* A, const bf16* B, long sA, long sB, long sO,
                         int K, int ldo, void* o, const float* bias, const float* aux,
                         float* aux2, dim3 grid) {
    GemmP gp;
    gp.A = A; gp.B = B; gp.sA = sA; gp.sB = sB; gp.sO = sO;
    gp.K = K; gp.ldo = ldo; gp.out = o; gp.bias = bias; gp.aux = aux; gp.aux2 = aux2;
    switch (epi) {
      case 0: gemm_bt<0><<<grid, 256, 0, stream>>>(gp); break;
      case 1: gemm_bt<1><<<grid, 256, 0, stream>>>(gp); break;
      case 2: gemm_bt<2><<<grid, 256, 0, stream>>>(gp); break;
      case 3: gemm_bt<3><<<grid, 256, 0, stream>>>(gp); break;
      case 4: gemm_bt<4><<<grid, 256, 0, stream>>>(gp); break;
      case 5: gemm_bt<5><<<grid, 256, 0, stream>>>(gp); break;
    }
  };

  dim3 tb(32, 8);
  // weight prep (per call; weights are inputs)
  transpose_cast<float><<<dim3(32, 4, 4), tb, 0, stream>>>(wq, wqT, 128, 1024, 131072, 131072);
  transpose_cast<float><<<dim3(32, 4, 4), tb, 0, stream>>>(wk, wkT, 128, 1024, 131072, 131072);
  transpose_cast<float><<<dim3(32, 4, 4), tb, 0, stream>>>(wv, wvT, 128, 1024, 131072, 131072);
  transpose_cast<float><<<dim3(4, 32, 4), tb, 0, stream>>>(wo, woT, 1024, 128, 131072, 131072);
  transpose_cast<float><<<dim3(16, 4, 4), tb, 0, stream>>>(w1, w1T, 128, 512, 65536, 65536);
  transpose_cast<float><<<dim3(4, 16, 4), tb, 0, stream>>>(w2, w2T, 512, 128, 65536, 65536);
  pm_prep<<<dim3(640, 4), 128, 0, stream>>>(proj, pmn);

  enc_k<<<8192, 128, 0, stream>>>(x, enc_w, enc_b, y);

  for (int i = 0; i < 4; ++i) {
    const bf16* wqTl = wqT + (long)i * 131072;
    const bf16* wkTl = wkT + (long)i * 131072;
    const bf16* wvTl = wvT + (long)i * 131072;
    const bf16* woTl = woT + (long)i * 131072;
    const bf16* w1Tl = w1T + (long)i * 65536;
    const bf16* w2Tl = w2T + (long)i * 65536;
    const bf16* pml  = pmn + (long)i * 81920;

    ln_k<<<2048, 256, 0, stream>>>(y, ln1_g + i * 128, ln1_b + i * 128, hbf);
    // q,k,v : [8192,128]@[128,1024] -> scatter to [b,h,n,d]
    launch_gemm(1, hbf, wqTl, 0, 0, 0, 128, 0, qb, bq + i * 1024, nullptr, nullptr, dim3(8, 64, 1));
    launch_gemm(1, hbf, wkTl, 0, 0, 0, 128, 0, kb, bk + i * 1024, nullptr, nullptr, dim3(8, 64, 1));
    launch_gemm(1, hbf, wvTl, 0, 0, 0, 128, 0, vb, bv + i * 1024, nullptr, nullptr, dim3(8, 64, 1));
    // v^T per (b,h): [2048,128] -> [128,2048]
    transpose_cast<bf16><<<dim3(4, 64, 32), tb, 0, stream>>>(vb, vt, 2048, 128, 262144, 262144);
    diag_kernel<<<4096, 256, 0, stream>>>(qb, diagq);
    diag_kernel<<<4096, 256, 0, stream>>>(kb, diagk);
    // xp_k^T[bh] = pm_n @ k^T -> [640,2048], fused masked tile-max
    launch_gemm(5, pml, kb, 0, 262144, 1310720, 128, 2048, xqk, nullptr, nullptr, tilemax, dim3(16, 5, 32));
    kmax2_k<<<32, 64, 0, stream>>>(tilemax, mxk);
    ktrans_k<<<dim3(640, 32), 256, 0, stream>>>(xqk, diagk, mxk, ksum);
    // ctx^T[bh] = v^T @ kf^T^T : A=vt[128,2048], B=kf[640,2048] -> [128,640]
    launch_gemm(0, vt, xqk, 262144, 1310720, 81920, 2048, 640, ctxt, nullptr, nullptr, nullptr, dim3(5, 1, 32));
    // xp_q = q @ pm_n^T : [65536,128]@[640,128]^T -> [65536,640]
    launch_gemm(0, qb, pml, 0, 0, 0, 128, 640, xqk, nullptr, nullptr, nullptr, dim3(5, 512, 1));
    qtrans_k<<<16384, 256, 0, stream>>>(xqk, diagq, ksum, dsum);
    // o[bh] = qf @ ctx^T^T : A=qf[2048,640], B=ctxt[128,640] -> scatter [b,n,h*128+d], *dinv
    launch_gemm(2, xqk, ctxt, 1310720, 81920, 0, 640, 0, ob, nullptr, dsum, nullptr, dim3(1, 16, 32));
    // y += o @ wo + bo
    launch_gemm(3, ob, woTl, 0, 0, 0, 1024, 128, y, bo + i * 128, nullptr, nullptr, dim3(1, 64, 1));
    ln_k<<<2048, 256, 0, stream>>>(y, ln2_g + i * 128, ln2_b + i * 128, hbf);
    // g = gelu(h@w1+b1)
    launch_gemm(4, hbf, w1Tl, 0, 0, 0, 128, 512, gb, b1 + i * 512, nullptr, nullptr, dim3(4, 64, 1));
    // y += g@w2 + b2
    launch_gemm(3, gb, w2Tl, 0, 0, 0, 512, 128, y, b2 + i * 128, nullptr, nullptr, dim3(1, 64, 1));
  }

  dec_kernel<<<2048, 256, 0, stream>>>(y, dec_w, dec_b, out);
}

// Round 14
// 1380.928 us; speedup vs baseline: 1.2789x; 1.0429x over previous
//
#include <hip/hip_runtime.h>
#include <math.h>

typedef __bf16 bf16;
typedef __bf16 bf16x8 __attribute__((ext_vector_type(8)));
typedef float f32x4 __attribute__((ext_vector_type(4)));

struct GemmP {
  const bf16* A;
  const bf16* B;
  long sA, sB, sO;   // batch strides in elements
  int K, ldo;
  void* out;
  const float* bias;
  const float* aux;  // dsum for EPI 2
  float* aux2;       // tilemax out for EPI 5
};

// fast gelu: tanh via native exp (bf16-grade precision)
__device__ __forceinline__ float gelu_f(float x) {
  float a = 0.7978845608028654f * (x + 0.044715f * x * x * x);
  float e = __expf(-2.f * fabsf(a));
  float th = __builtin_copysignf((1.f - e) / (1.f + e), a);
  return 0.5f * x * (1.f + th);
}

// async global->LDS, 16B per lane; LDS dest = wave-uniform base + lane*16
__device__ __forceinline__ void gload16(const bf16* g, bf16* l) {
  __builtin_amdgcn_global_load_lds(
      (const __attribute__((address_space(1))) void*)g,
      (__attribute__((address_space(3))) void*)l, 16, 0, 0);
}

// C = A @ B^T, A:[M,K] bf16 (lda=K), B:[N,K] bf16 (ldb=K), f32 accum.
// 128x128 tile, BK=64, 4 waves, 16x16x32 bf16 MFMA, global_load_lds staging (m97 structure).
// EPI: 0 = store bf16 (z*sO + row*ldo + col)
//      1 = +bias, scatter [b,n,h*128+d] -> [b,h,n,d] bf16   (M=8192 rows = b*2048+n)
//      2 = *1/aux[z*2048+row], scatter -> o[b,n, h*128+col]  (batch z = b*8+h, M=2048)
//      3 = y[row*ldo+col] += acc + bias[col]  (f32 out)
//      4 = store bf16 gelu(acc + bias[col])
//      5 = EPI0 store + masked (row<621) block max -> aux2[z*80 + mt*16 + nt]
template<int EPI>
__global__ __launch_bounds__(256) void gemm_bt(GemmP p) {
  __shared__ bf16 As[128][64];   // linear: global_load_lds dest must be unpadded
  __shared__ bf16 Bs[128][64];
  const int nt = blockIdx.x, mt = blockIdx.y, z = blockIdx.z;
  const bf16* A = p.A + (long)z * p.sA + (long)mt * 128 * p.K;
  const bf16* B = p.B + (long)z * p.sB + (long)nt * 128 * p.K;
  const int t = threadIdx.x;
  const int w = t >> 6, lane = t & 63;
  const int lr = lane & 15, lg = lane >> 4;
  const int wm = (w >> 1) * 64, wn = (w & 1) * 64;
  const int srow = lane >> 3, scol = (lane & 7) * 8;   // staging: 8 rows/wave-issue

  f32x4 acc[4][4] = {};

  for (int k0 = 0; k0 < p.K; k0 += 64) {
#pragma unroll
    for (int i = 0; i < 4; ++i) {
      int r0 = i * 32 + w * 8;
      gload16(A + (long)(r0 + srow) * p.K + k0 + scol, &As[r0][0]);
      gload16(B + (long)(r0 + srow) * p.K + k0 + scol, &Bs[r0][0]);
    }
    __syncthreads();
#pragma unroll
    for (int ks = 0; ks < 64; ks += 32) {
      bf16x8 af[4], bfr[4];
#pragma unroll
      for (int i = 0; i < 4; ++i) af[i] = *(const bf16x8*)(&As[wm + i * 16 + lr][ks + lg * 8]);
#pragma unroll
      for (int i = 0; i < 4; ++i) bfr[i] = *(const bf16x8*)(&Bs[wn + i * 16 + lr][ks + lg * 8]);
#pragma unroll
      for (int i = 0; i < 4; ++i)
#pragma unroll
        for (int j = 0; j < 4; ++j)
          acc[i][j] = __builtin_amdgcn_mfma_f32_16x16x32_bf16(af[i], bfr[j], acc[i][j], 0, 0, 0);
    }
    __syncthreads();
  }

  float tmax = -3.0e38f;
#pragma unroll
  for (int i = 0; i < 4; ++i) {
#pragma unroll
    for (int j = 0; j < 4; ++j) {
#pragma unroll
      for (int e = 0; e < 4; ++e) {
        int grow = mt * 128 + wm + i * 16 + lg * 4 + e;
        int gcol = nt * 128 + wn + j * 16 + lr;
        float v = acc[i][j][e];
        if constexpr (EPI == 0) {
          ((bf16*)p.out)[(long)z * p.sO + (long)grow * p.ldo + gcol] = (bf16)v;
        } else if constexpr (EPI == 1) {
          v += p.bias[gcol];
          int b = grow >> 11, n = grow & 2047, hh = gcol >> 7, d = gcol & 127;
          ((bf16*)p.out)[(((long)(b * 8 + hh) * 2048 + n) << 7) + d] = (bf16)v;
        } else if constexpr (EPI == 2) {
          float ds = p.aux[(long)z * 2048 + grow];
          int b = z >> 3, hh = z & 7;
          ((bf16*)p.out)[((long)(b * 2048 + grow)) * 1024 + hh * 128 + gcol] = (bf16)(v / ds);
        } else if constexpr (EPI == 3) {
          float* Y = (float*)p.out;
          Y[(long)grow * p.ldo + gcol] += v + p.bias[gcol];
        } else if constexpr (EPI == 4) {
          float vv = v + p.bias[gcol];
          ((bf16*)p.out)[(long)grow * p.ldo + gcol] = (bf16)gelu_f(vv);
        } else {  // EPI 5
          ((bf16*)p.out)[(long)z * p.sO + (long)grow * p.ldo + gcol] = (bf16)v;
          if (grow < 621) tmax = fmaxf(tmax, v);
        }
      }
    }
  }
  if constexpr (EPI == 5) {
    for (int o = 32; o; o >>= 1) tmax = fmaxf(tmax, __shfl_xor(tmax, o));
    __shared__ float red4[4];
    if (!lane) red4[w] = tmax;
    __syncthreads();
    if (!t) p.aux2[(long)z * 80 + mt * 16 + nt] =
        fmaxf(fmaxf(red4[0], red4[1]), fmaxf(red4[2], red4[3]));
  }
}

// out[z][c][r] = (bf16) in[z][r][c] ; R,C multiples of 32
template<typename TIN>
__global__ void transpose_cast(const TIN* __restrict__ in, bf16* __restrict__ out,
                               int R, int C, long sIn, long sOut) {
  __shared__ float tile[32][33];
  in += (long)blockIdx.z * sIn;
  out += (long)blockIdx.z * sOut;
  int r0 = blockIdx.y * 32, c0 = blockIdx.x * 32;
  int tx = threadIdx.x, ty = threadIdx.y;  // (32,8)
#pragma unroll
  for (int i = 0; i < 4; ++i)
    tile[ty + i * 8][tx] = (float)in[(long)(r0 + ty + i * 8) * C + c0 + tx];
  __syncthreads();
#pragma unroll
  for (int i = 0; i < 4; ++i)
    out[(long)(c0 + ty + i * 8) * R + r0 + tx] = (bf16)tile[tx][ty + i * 8];
}

// pm_n[l][f][d] = f<621 ? proj[l][f][d]*norm : 0   (norm = 128^-0.25)
__global__ void pm_prep(const float* __restrict__ proj, bf16* __restrict__ out) {
  int f = blockIdx.x, z = blockIdx.y, d = threadIdx.x;  // block 128
  float v = (f < 621) ? proj[((long)z * 621 + f) * 128 + d] * 0.29730177875068026f : 0.f;
  out[((long)z * 640 + f) * 128 + d] = (bf16)v;
}

__global__ __launch_bounds__(128) void enc_k(const float* __restrict__ x, const float* __restrict__ w,
                                             const float* __restrict__ b, float* __restrict__ y) {
  __shared__ float xs[40];
  int r = blockIdx.x, t = threadIdx.x;
  if (t < 35) xs[t] = x[(long)r * 35 + t];
  __syncthreads();
  float acc = b[t];
#pragma unroll
  for (int m = 0; m < 35; ++m) acc += xs[m] * w[m * 128 + t];
  y[(long)r * 128 + t] = acc;
}

__global__ __launch_bounds__(256) void ln_k(const float* __restrict__ y, const float* __restrict__ g,
                                            const float* __restrict__ b, bf16* __restrict__ out) {
  int w = threadIdx.x >> 6, lane = threadIdx.x & 63;
  long r = (long)blockIdx.x * 4 + w;
  const float* yr = y + r * 128;
  float e0 = yr[lane], e1 = yr[lane + 64];
  float s = e0 + e1, q = e0 * e0 + e1 * e1;
  for (int o = 32; o; o >>= 1) { s += __shfl_xor(s, o); q += __shfl_xor(q, o); }
  float mean = s * (1.f / 128.f);
  float var = q * (1.f / 128.f) - mean * mean;
  float rs = rsqrtf(var + 1e-5f);
  out[r * 128 + lane] = (bf16)((e0 - mean) * rs * g[lane] + b[lane]);
  out[r * 128 + lane + 64] = (bf16)((e1 - mean) * rs * g[lane + 64] + b[lane + 64]);
}

// diag[r] = 0.5*norm^2 * sum_d q[r,d]^2 ; 16 lanes x bf16x8 per row, 16 rows/block
__global__ __launch_bounds__(256) void diag_kernel(const bf16* __restrict__ q, float* __restrict__ dg) {
  int wv = threadIdx.x >> 6, lane = threadIdx.x & 63;
  int sub = lane >> 4, sl = lane & 15;
  long r = (long)blockIdx.x * 16 + wv * 4 + sub;
  bf16x8 v = *(const bf16x8*)(q + r * 128 + sl * 8);
  float s = 0.f;
#pragma unroll
  for (int j = 0; j < 8; ++j) { float e = (float)v[j]; s += e * e; }
  for (int o = 8; o; o >>= 1) s += __shfl_xor(s, o);
  if (!sl) dg[r] = s * 0.04419417382415922f;
}

// reduce 80 tile-maxes per bh
__global__ __launch_bounds__(64) void kmax2_k(const float* __restrict__ tm, float* __restrict__ mxk) {
  int bh = blockIdx.x, lane = threadIdx.x;
  const float* p = tm + bh * 80;
  float m = p[lane];
  if (lane < 16) m = fmaxf(m, p[64 + lane]);
  for (int o = 32; o; o >>= 1) m = fmaxf(m, __shfl_xor(m, o));
  if (!lane) mxk[bh] = m;
}

// in-place vectorized: xkt[bh][f][n] -> kf; pad rows -> 0; ksum[bh][f] = sum_n kf
__global__ __launch_bounds__(256) void ktrans_k(bf16* __restrict__ xkt, const float* __restrict__ diagk,
                                                const float* __restrict__ mxk, float* __restrict__ ksum) {
  int f = blockIdx.x, bh = blockIdx.y, t = threadIdx.x;
  bf16* row = xkt + ((long)bh * 640 + f) * 2048;
  float acc = 0.f;
  if (f < 621) {
    float mx = mxk[bh];
    const float* dgp = diagk + (long)bh * 2048 + t * 8;
    float4 d0 = *(const float4*)(dgp);
    float4 d1 = *(const float4*)(dgp + 4);
    float dd[8] = {d0.x, d0.y, d0.z, d0.w, d1.x, d1.y, d1.z, d1.w};
    bf16x8 v = *(const bf16x8*)(row + t * 8);
    bf16x8 o;
#pragma unroll
    for (int j = 0; j < 8; ++j) {
      float kf = 0.040128573f * (__expf((float)v[j] - dd[j] - mx) + 1e-4f);
      bf16 kb = (bf16)kf;
      o[j] = kb;
      acc += (float)kb;
    }
    *(bf16x8*)(row + t * 8) = o;
  } else {
    bf16x8 zz = {};
    *(bf16x8*)(row + t * 8) = zz;
  }
  for (int o = 32; o; o >>= 1) acc += __shfl_xor(acc, o);
  __shared__ float red[4];
  if (!(t & 63)) red[t >> 6] = acc;
  __syncthreads();
  if (!t) ksum[(long)bh * 640 + f] = red[0] + red[1] + red[2] + red[3];
}

// fused in-place: rowmax + transform + dsum. One wave per row (4 rows/block).
__global__ __launch_bounds__(256) void qtrans_k(bf16* __restrict__ xq, const float* __restrict__ diagq,
                                                const float* __restrict__ ksum, float* __restrict__ dsum) {
  int wv = threadIdx.x >> 6, lane = threadIdx.x & 63;
  long r = (long)blockIdx.x * 4 + wv;
  int bh = (int)(r >> 11);
  bf16* row = xq + r * 640;
  const float* ks = ksum + (long)bh * 640;
  bool has2 = lane < 16;
  bf16x8 v0 = *(const bf16x8*)(row + lane * 8);
  bf16x8 v1 = {};
  if (has2) v1 = *(const bf16x8*)(row + 512 + lane * 8);
  float m = -3.0e38f;
#pragma unroll
  for (int j = 0; j < 8; ++j) m = fmaxf(m, (float)v0[j]);  // f<512 always valid
  if (has2) {
#pragma unroll
    for (int j = 0; j < 8; ++j) {
      int f = 512 + lane * 8 + j;
      if (f < 621) m = fmaxf(m, (float)v1[j]);
    }
  }
  for (int o = 32; o; o >>= 1) m = fmaxf(m, __shfl_xor(m, o));
  float base = -diagq[r] - m;
  float4 ka = *(const float4*)(ks + lane * 8);
  float4 kb2 = *(const float4*)(ks + lane * 8 + 4);
  float kk[8] = {ka.x, ka.y, ka.z, ka.w, kb2.x, kb2.y, kb2.z, kb2.w};
  float acc = 0.f;
  bf16x8 o0, o1;
#pragma unroll
  for (int j = 0; j < 8; ++j) {
    float qf = 0.040128573f * (__expf((float)v0[j] + base) + 1e-4f);
    bf16 qb = (bf16)qf;
    o0[j] = qb;
    acc += (float)qb * kk[j];
  }
  *(bf16x8*)(row + lane * 8) = o0;
  if (has2) {
    float4 kc = *(const float4*)(ks + 512 + lane * 8);
    float4 kd = *(const float4*)(ks + 512 + lane * 8 + 4);
    float k2[8] = {kc.x, kc.y, kc.z, kc.w, kd.x, kd.y, kd.z, kd.w};
#pragma unroll
    for (int j = 0; j < 8; ++j) {
      int f = 512 + lane * 8 + j;
      if (f < 621) {
        float qf = 0.040128573f * (__expf((float)v1[j] + base) + 1e-4f);
        bf16 qb = (bf16)qf;
        o1[j] = qb;
        acc += (float)qb * k2[j];
      } else {
        o1[j] = (bf16)0.f;
      }
    }
    *(bf16x8*)(row + 512 + lane * 8) = o1;
  }
  for (int o = 32; o; o >>= 1) acc += __shfl_xor(acc, o);
  if (!lane) dsum[r] = acc;
}

__global__ __launch_bounds__(256) void dec_kernel(const float* __restrict__ y, const float* __restrict__ w,
                                                  const float* __restrict__ b, float* __restrict__ out) {
  int wv = threadIdx.x >> 6, lane = threadIdx.x & 63;
  long r = (long)blockIdx.x * 4 + wv;
  const float* yr = y + r * 128;
  float s = yr[lane] * w[lane] + yr[lane + 64] * w[lane + 64];
  for (int o = 32; o; o >>= 1) s += __shfl_xor(s, o);
  if (!lane) out[r] = s + b[0];
}

extern "C" void kernel_launch(void* const* d_in, const int* in_sizes, int n_in,
                              void* d_out, int out_size, void* d_ws, size_t ws_size,
                              hipStream_t stream) {
  (void)in_sizes; (void)n_in; (void)out_size; (void)ws_size;
  const float* x     = (const float*)d_in[0];
  const float* enc_w = (const float*)d_in[1];
  const float* enc_b = (const float*)d_in[2];
  const float* ln1_g = (const float*)d_in[3];
  const float* ln1_b = (const float*)d_in[4];
  const float* wq    = (const float*)d_in[5];
  const float* bq    = (const float*)d_in[6];
  const float* wk    = (const float*)d_in[7];
  const float* bk    = (const float*)d_in[8];
  const float* wv    = (const float*)d_in[9];
  const float* bv    = (const float*)d_in[10];
  const float* wo    = (const float*)d_in[11];
  const float* bo    = (const float*)d_in[12];
  const float* ln2_g = (const float*)d_in[13];
  const float* ln2_b = (const float*)d_in[14];
  const float* w1    = (const float*)d_in[15];
  const float* b1    = (const float*)d_in[16];
  const float* w2    = (const float*)d_in[17];
  const float* b2    = (const float*)d_in[18];
  const float* proj  = (const float*)d_in[19];
  const float* dec_w = (const float*)d_in[20];
  const float* dec_b = (const float*)d_in[21];
  float* out = (float*)d_out;

  char* ws = (char*)d_ws;
  size_t off = 0;
  auto alloc = [&](size_t bytes) -> void* {
    void* p = ws + off;
    off = (off + bytes + 255) & ~(size_t)255;
    return p;
  };

  float* y    = (float*)alloc(4ul * 8192 * 128);
  bf16* hbf   = (bf16*)alloc(2ul * 8192 * 128);
  bf16* qb    = (bf16*)alloc(2ul * 65536 * 128);
  bf16* kb    = (bf16*)alloc(2ul * 65536 * 128);   // reused as o_buf
  bf16* vb    = (bf16*)alloc(2ul * 65536 * 128);
  bf16* vt    = (bf16*)alloc(2ul * 65536 * 128);   // reused as g_buf
  bf16* xqk   = (bf16*)alloc(2ul * 65536 * 640);   // xp_k^T then xp_q/qf
  bf16* ctxt  = (bf16*)alloc(2ul * 32 * 128 * 640);
  float* diagq = (float*)alloc(4ul * 65536);
  float* diagk = (float*)alloc(4ul * 65536);
  float* tilemax = (float*)alloc(4ul * 32 * 80);
  float* mxk   = (float*)alloc(4ul * 32);
  float* ksum  = (float*)alloc(4ul * 32 * 640);
  float* dsum  = (float*)alloc(4ul * 65536);
  bf16* wqT = (bf16*)alloc(2ul * 4 * 1024 * 128);
  bf16* wkT = (bf16*)alloc(2ul * 4 * 1024 * 128);
  bf16* wvT = (bf16*)alloc(2ul * 4 * 1024 * 128);
  bf16* woT = (bf16*)alloc(2ul * 4 * 128 * 1024);
  bf16* w1T = (bf16*)alloc(2ul * 4 * 512 * 128);
  bf16* w2T = (bf16*)alloc(2ul * 4 * 128 * 512);
  bf16* pmn = (bf16*)alloc(2ul * 4 * 640 * 128);
  bf16* ob = kb;
  bf16* gb = vt;

  auto launch_gemm = [&](int epi, const bf16* A, const bf16* B, long sA, long sB, long sO,
                         int K, int ldo, void* o, const float* bias, const float* aux,
                         float* aux2, dim3 grid) {
    GemmP gp;
    gp.A = A; gp.B = B; gp.sA = sA; gp.sB = sB; gp.sO = sO;
    gp.K = K; gp.ldo = ldo; gp.out = o; gp.bias = bias; gp.aux = aux; gp.aux2 = aux2;
    switch (epi) {
      case 0: gemm_bt<0><<<grid, 256, 0, stream>>>(gp); break;
      case 1: gemm_bt<1><<<grid, 256, 0, stream>>>(gp); break;
      case 2: gemm_bt<2><<<grid, 256, 0, stream>>>(gp); break;
      case 3: gemm_bt<3><<<grid, 256, 0, stream>>>(gp); break;
      case 4: gemm_bt<4><<<grid, 256, 0, stream>>>(gp); break;
      case 5: gemm_bt<5><<<grid, 256, 0, stream>>>(gp); break;
    }
  };

  dim3 tb(32, 8);
  // weight prep (per call; weights are inputs)
  transpose_cast<float><<<dim3(32, 4, 4), tb, 0, stream>>>(wq, wqT, 128, 1024, 131072, 131072);
  transpose_cast<float><<<dim3(32, 4, 4), tb, 0, stream>>>(wk, wkT, 128, 1024, 131072, 131072);
  transpose_cast<float><<<dim3(32, 4, 4), tb, 0, stream>>>(wv, wvT, 128, 1024, 131072, 131072);
  transpose_cast<float><<<dim3(4, 32, 4), tb, 0, stream>>>(wo, woT, 1024, 128, 131072, 131072);
  transpose_cast<float><<<dim3(16, 4, 4), tb, 0, stream>>>(w1, w1T, 128, 512, 65536, 65536);
  transpose_cast<float><<<dim3(4, 16, 4), tb, 0, stream>>>(w2, w2T, 512, 128, 65536, 65536);
  pm_prep<<<dim3(640, 4), 128, 0, stream>>>(proj, pmn);

  enc_k<<<8192, 128, 0, stream>>>(x, enc_w, enc_b, y);

  for (int i = 0; i < 4; ++i) {
    const bf16* wqTl = wqT + (long)i * 131072;
    const bf16* wkTl = wkT + (long)i * 131072;
    const bf16* wvTl = wvT + (long)i * 131072;
    const bf16* woTl = woT + (long)i * 131072;
    const bf16* w1Tl = w1T + (long)i * 65536;
    const bf16* w2Tl = w2T + (long)i * 65536;
    const bf16* pml  = pmn + (long)i * 81920;

    ln_k<<<2048, 256, 0, stream>>>(y, ln1_g + i * 128, ln1_b + i * 128, hbf);
    // q,k,v : [8192,128]@[128,1024] -> scatter to [b,h,n,d]
    launch_gemm(1, hbf, wqTl, 0, 0, 0, 128, 0, qb, bq + i * 1024, nullptr, nullptr, dim3(8, 64, 1));
    launch_gemm(1, hbf, wkTl, 0, 0, 0, 128, 0, kb, bk + i * 1024, nullptr, nullptr, dim3(8, 64, 1));
    launch_gemm(1, hbf, wvTl, 0, 0, 0, 128, 0, vb, bv + i * 1024, nullptr, nullptr, dim3(8, 64, 1));
    // v^T per (b,h): [2048,128] -> [128,2048]
    transpose_cast<bf16><<<dim3(4, 64, 32), tb, 0, stream>>>(vb, vt, 2048, 128, 262144, 262144);
    diag_kernel<<<4096, 256, 0, stream>>>(qb, diagq);
    diag_kernel<<<4096, 256, 0, stream>>>(kb, diagk);
    // xp_k^T[bh] = pm_n @ k^T -> [640,2048], fused masked tile-max
    launch_gemm(5, pml, kb, 0, 262144, 1310720, 128, 2048, xqk, nullptr, nullptr, tilemax, dim3(16, 5, 32));
    kmax2_k<<<32, 64, 0, stream>>>(tilemax, mxk);
    ktrans_k<<<dim3(640, 32), 256, 0, stream>>>(xqk, diagk, mxk, ksum);
    // ctx^T[bh] = v^T @ kf^T^T : A=vt[128,2048], B=kf[640,2048] -> [128,640]
    launch_gemm(0, vt, xqk, 262144, 1310720, 81920, 2048, 640, ctxt, nullptr, nullptr, nullptr, dim3(5, 1, 32));
    // xp_q = q @ pm_n^T : [65536,128]@[640,128]^T -> [65536,640]
    launch_gemm(0, qb, pml, 0, 0, 0, 128, 640, xqk, nullptr, nullptr, nullptr, dim3(5, 512, 1));
    qtrans_k<<<16384, 256, 0, stream>>>(xqk, diagq, ksum, dsum);
    // o[bh] = qf @ ctx^T^T : A=qf[2048,640], B=ctxt[128,640] -> scatter [b,n,h*128+d], *dinv
    launch_gemm(2, xqk, ctxt, 1310720, 81920, 0, 640, 0, ob, nullptr, dsum, nullptr, dim3(1, 16, 32));
    // y += o @ wo + bo
    launch_gemm(3, ob, woTl, 0, 0, 0, 1024, 128, y, bo + i * 128, nullptr, nullptr, dim3(1, 64, 1));
    ln_k<<<2048, 256, 0, stream>>>(y, ln2_g + i * 128, ln2_b + i * 128, hbf);
    // g = gelu(h@w1+b1)
    launch_gemm(4, hbf, w1Tl, 0, 0, 0, 128, 512, gb, b1 + i * 512, nullptr, nullptr, dim3(4, 64, 1));
    // y += g@w2 + b2
    launch_gemm(3, gb, w2Tl, 0, 0, 0, 512, 128, y, b2 + i * 128, nullptr, nullptr, dim3(1, 64, 1));
  }

  dec_kernel<<<2048, 256, 0, stream>>>(y, dec_w, dec_b, out);
}